// Round 20
// baseline (41.004 us; speedup 1.0000x reference)
//
#include <hip/hip_runtime.h>
#include <hip/hip_bf16.h>

typedef __attribute__((ext_vector_type(8))) short bf16x8;
typedef __attribute__((ext_vector_type(4))) float f32x4;
typedef __attribute__((ext_vector_type(2))) float f32x2;
typedef unsigned int uint32;
typedef unsigned short ushort_t;
typedef __attribute__((ext_vector_type(4))) uint32 u32x4;

#define SB0() __builtin_amdgcn_sched_barrier(0)

__device__ __forceinline__ ushort_t f2bf(float f) {
    unsigned int u = __float_as_uint(f);
    u = (u + 0x7FFFu + ((u >> 16) & 1u)) >> 16;
    return (ushort_t)u;
}

__device__ __forceinline__ uint32 cvt_pk_bf16(float lo, float hi) {
    uint32 r;
    asm("v_cvt_pk_bf16_f32 %0, %1, %2" : "=v"(r) : "v"(lo), "v"(hi));
    return r;
}

// Forced-issue 16B global load (cannot be sunk by the scheduler); value is
// consumed only after an explicit full-drain vmcnt(0) -> count-independent,
// spill-safe (any extra VMEM just gets drained too).
template<int IMM>
__device__ __forceinline__ u32x4 gload(const char* p) {
    u32x4 r;
    asm volatile("global_load_dwordx4 %0, %1, off offset:%2"
                 : "=v"(r) : "v"(p), "n"(IMM));
    return r;
}

__device__ __forceinline__ void gload_lds16(const void* g, void* l) {
    __builtin_amdgcn_global_load_lds(
        (const __attribute__((address_space(1))) uint32*)g,
        (__attribute__((address_space(3))) uint32*)l, 16, 0, 0);
}

// Fused prep (R12/R15-proven):
//  blocks 0..4095: transpose x NCHW fp32 -> NHWC bf16 with per-record 16B
//    sub-chunk XOR swizzle (chunk (c>>3) stored at (c>>3)^(x&7)).
//  blocks 4096..4671: repack weight fragment-major (R5 layout).
__global__ __launch_bounds__(256) void prep_all(const float* __restrict__ x,
                                                const float* __restrict__ w,
                                                ushort_t* __restrict__ xt,
                                                ushort_t* __restrict__ wT2) {
    int bi = blockIdx.x;
    int t = threadIdx.x;
    if (bi >= 4096) {
        int idx = (bi - 4096) * 256 + t;   // 0..147455
        int j  = idx & 7;
        int f  = (idx >> 3) & 127;
        int lu = (idx >> 10) & 3;
        int ks = (idx >> 12) & 3;
        int tap = idx >> 14;
        int c = ks * 32 + lu * 8 + j;
        wT2[idx] = f2bf(w[((size_t)f * 128 + c) * 9 + tap]);
        return;
    }
    __shared__ float tile[32][33];
    int b = bi & 7;
    int r2 = bi >> 3;
    int wb = r2 & 1, cb = (r2 >> 1) & 3, y = r2 >> 3;
    int lw = t & 31, lc = t >> 5;
    #pragma unroll
    for (int pass = 0; pass < 4; ++pass) {
        int c = cb * 32 + lc + pass * 8;
        tile[lc + pass * 8][lw] = x[(((size_t)b * 128 + c) * 64 + y) * 64 + wb * 32 + lw];
    }
    __syncthreads();
    int cc = t & 31, xl = t >> 5;
    #pragma unroll
    for (int pass = 0; pass < 4; ++pass) {
        int xll = xl + pass * 8;
        int xx = wb * 32 + xll;
        int c = cb * 32 + cc;
        int c2 = (((c >> 3) ^ (xx & 7)) << 3) | (c & 7);   // record-local swizzle
        xt[(((size_t)b * 64 + y) * 64 + xx) * 128 + c2] = f2bf(tile[cc][xll]);
    }
}

__device__ __forceinline__ bf16x8 interp4(u32x4 c0, u32x4 c1, u32x4 c2, u32x4 c3,
                                          f32x4 wv) {
    uint32 rr[4];
    #pragma unroll
    for (int i = 0; i < 4; ++i) {
        f32x2 a, s;
        uint32 u = c0[i];
        a.x = __uint_as_float(u << 16); a.y = __uint_as_float(u & 0xffff0000u);
        s = a * wv.x;
        u = c1[i];
        a.x = __uint_as_float(u << 16); a.y = __uint_as_float(u & 0xffff0000u);
        s += a * wv.y;
        u = c2[i];
        a.x = __uint_as_float(u << 16); a.y = __uint_as_float(u & 0xffff0000u);
        s += a * wv.z;
        u = c3[i];
        a.x = __uint_as_float(u << 16); a.y = __uint_as_float(u & 0xffff0000u);
        s += a * wv.w;
        rr[i] = cvt_pk_bf16(s.x, s.y);
    }
    u32x4 q = {rr[0], rr[1], rr[2], rr[3]};
    return __builtin_bit_cast(bf16x8, q);
}

// Block = 1024 thr = 16 waves = {4 pxg} x {4 ks}; one (b,ho) row (64 px x 128 F).
// Wave tile: 16px x 128F x 32ch, zero gather/interp duplication.
// 9-row LDS window (wave-level fallback ~2%, execz-skipped).
// Per tap: 8 A-fragment loads issued via asm volatile at tap top (un-sinkable),
// consumed after interp + vmcnt(0)+SB0 full drain (count-independent, safe
// under spills/fallback loads). Session-best structure (R15/R19 family).
__global__ __launch_bounds__(1024, 4) void dcn_main(
    const float* __restrict__ offset, const float* __restrict__ mask,
    const ushort_t* __restrict__ xt, const ushort_t* __restrict__ wT2,
    float* __restrict__ out)
{
    __shared__ ushort_t xwin[9 * 64 * 128];  // 144 KB; overlaid by `red` in epilogue
    __shared__ float  pws_l[9][64][4];       // 9 KB
    __shared__ uint32 pos_l[9][64];          // 2.25 KB

    int bi = blockIdx.x;
    int b = bi & 7, ho = bi >> 3;            // batch <-> XCD
    int t = threadIdx.x, lane = t & 63, wid = t >> 6;
    int pxg = wid & 3, ks = wid >> 2;
    int p = lane & 15, lu = lane >> 4;
    int px = pxg * 16 + p;
    int row0 = min(max(ho - 4, 0), 55);      // window rows [row0, row0+9)

    const char* xgb = (const char*)xt + (size_t)b * (64 * 64 * 256);

    // ---- prologue: stage 9-row window (async) + sampling params ----
    {
        const char* ws = xgb + ((size_t)row0 << 14);
        #pragma unroll
        for (int r = 0; r < 9; ++r)
            gload_lds16(ws + (r * 1024 + t) * 16, (char*)xwin + (r * 1024 + t) * 16);
    }
    if (t < 576) {
        int k = t >> 6, pi = t & 63;
        int ki = k / 3, kj = k - ki * 3;
        float dy = offset[(((size_t)b * 18 + 2 * k)     * 64 + ho) * 64 + pi];
        float dx = offset[(((size_t)b * 18 + 2 * k + 1) * 64 + ho) * 64 + pi];
        float m  = mask  [(((size_t)b * 9  + k)         * 64 + ho) * 64 + pi];
        float py = (float)(ho - 1 + ki) + dy;
        float px_ = (float)(pi - 1 + kj) + dx;
        float y0f = floorf(py), x0f = floorf(px_);
        float ly = py - y0f, lx = px_ - x0f;
        float hy = 1.f - ly, hx = 1.f - lx;
        int y0 = (int)y0f, x0 = (int)x0f;
        int y1 = y0 + 1, x1 = x0 + 1;
        float vy0 = (y0 >= 0 && y0 < 64) ? 1.f : 0.f;
        float vy1 = (y1 >= 0 && y1 < 64) ? 1.f : 0.f;
        float vx0 = (x0 >= 0 && x0 < 64) ? 1.f : 0.f;
        float vx1 = (x1 >= 0 && x1 < 64) ? 1.f : 0.f;
        pws_l[k][pi][0] = hy * hx * m * vy0 * vx0;
        pws_l[k][pi][1] = hy * lx * m * vy0 * vx1;
        pws_l[k][pi][2] = ly * hx * m * vy1 * vx0;
        pws_l[k][pi][3] = ly * lx * m * vy1 * vx1;
        int y0c = min(max(y0, 0), 63), y1c = min(max(y1, 0), 63);
        int x0c = min(max(x0, 0), 63), x1c = min(max(x1, 0), 63);
        pos_l[k][pi] = (uint32)(y0c * 64 + x0c) | ((uint32)(y1c * 64 + x1c) << 16);
    }
    __syncthreads();   // window + params ready (drains global_load_lds)

    f32x4 acc[8];
    #pragma unroll
    for (int i = 0; i < 8; ++i) acc[i] = (f32x4){0.f, 0.f, 0.f, 0.f};

    int klu = ks * 64 + lu * 16;   // this lane's 16B slice within a 256B record
    const char* abase = (const char*)wT2 + (lu * 128 + p) * 16;

    #pragma unroll 1
    for (int tap = 0; tap < 9; ++tap) {
        // ---- issue this tap's 8 A-frag loads (asm: cannot be sunk) ----
        const char* ab = abase + (size_t)(tap * 4 + ks) * 8192;
        u32x4 a0 = gload<0>(ab),    a1 = gload<256>(ab);
        u32x4 a2 = gload<512>(ab),  a3 = gload<768>(ab);
        u32x4 a4 = gload<1024>(ab), a5 = gload<1280>(ab);
        u32x4 a6 = gload<1536>(ab), a7 = gload<1792>(ab);
        SB0();   // pin issue point; ~150-250cy of gather+interp follows

        // ---- B frag: 4-corner gather from LDS window + rare fixup ----
        uint32 pp = pos_l[tap][px];
        int i00 = pp & 0xffffu, i11 = pp >> 16;
        int y0c = i00 >> 6, x0c = i00 & 63;
        int y1c = i11 >> 6, x1c = i11 & 63;
        u32x4 g[4];
        uint32 rec[4];
        #pragma unroll
        for (int c = 0; c < 4; ++c) {
            int yc = (c < 2) ? y0c : y1c;
            int xc = (c & 1) ? x1c : x0c;
            int rl = yc - row0;
            int off = klu ^ ((xc & 7) << 4);
            bool inw = (unsigned)rl < 9u;
            rec[c] = (uint32)(((yc * 64 + xc) << 8) + off) | (inw ? 0x80000000u : 0u);
            const char* lp = (const char*)xwin + (((inw ? rl : 0) * 64 + xc) << 8) + off;
            g[c] = *(const u32x4*)lp;
        }
        #pragma unroll
        for (int c = 0; c < 4; ++c) {
            if (!(rec[c] & 0x80000000u))   // ~2%/wave, execz-skipped; loads are
                g[c] = *(const u32x4*)(xgb + (rec[c] & 0x7fffffffu));  // younger than A
        }
        f32x4 wv = *(const f32x4*)pws_l[tap][px];
        bf16x8 bb = interp4(g[0], g[1], g[2], g[3], wv);

        // ---- full drain: A-frags (and anything else) complete; rule #18 fence ----
        asm volatile("s_waitcnt vmcnt(0)" ::: "memory");
        SB0();

        acc[0] = __builtin_amdgcn_mfma_f32_16x16x32_bf16(__builtin_bit_cast(bf16x8, a0), bb, acc[0], 0, 0, 0);
        acc[1] = __builtin_amdgcn_mfma_f32_16x16x32_bf16(__builtin_bit_cast(bf16x8, a1), bb, acc[1], 0, 0, 0);
        acc[2] = __builtin_amdgcn_mfma_f32_16x16x32_bf16(__builtin_bit_cast(bf16x8, a2), bb, acc[2], 0, 0, 0);
        acc[3] = __builtin_amdgcn_mfma_f32_16x16x32_bf16(__builtin_bit_cast(bf16x8, a3), bb, acc[3], 0, 0, 0);
        acc[4] = __builtin_amdgcn_mfma_f32_16x16x32_bf16(__builtin_bit_cast(bf16x8, a4), bb, acc[4], 0, 0, 0);
        acc[5] = __builtin_amdgcn_mfma_f32_16x16x32_bf16(__builtin_bit_cast(bf16x8, a5), bb, acc[5], 0, 0, 0);
        acc[6] = __builtin_amdgcn_mfma_f32_16x16x32_bf16(__builtin_bit_cast(bf16x8, a6), bb, acc[6], 0, 0, 0);
        acc[7] = __builtin_amdgcn_mfma_f32_16x16x32_bf16(__builtin_bit_cast(bf16x8, a7), bb, acc[7], 0, 0, 0);
    }

    // ---- epilogue: 4-way ks reduce via LDS (overlay on xwin), stride 65 ----
    __syncthreads();
    float* red = (float*)xwin;   // 2 slots x [128 f][stride 65] = 66.5 KB <= 144 KB

    #define DUMP(SLOT)                                                          \
        do {                                                                    \
            _Pragma("unroll")                                                   \
            for (int ft = 0; ft < 8; ++ft)                                      \
                _Pragma("unroll")                                               \
                for (int r = 0; r < 4; ++r)                                     \
                    red[(SLOT) * 8320 + (ft * 16 + lu * 4 + r) * 65 + px] =     \
                        acc[ft][r];                                             \
        } while (0)
    #define ADDIN(SLOT)                                                         \
        do {                                                                    \
            _Pragma("unroll")                                                   \
            for (int ft = 0; ft < 8; ++ft)                                      \
                _Pragma("unroll")                                               \
                for (int r = 0; r < 4; ++r)                                     \
                    acc[ft][r] += red[(SLOT) * 8320                             \
                        + (ft * 16 + lu * 4 + r) * 65 + px];                    \
        } while (0)

    if (ks == 1) DUMP(0);
    if (ks == 3) DUMP(1);
    __syncthreads();
    if (ks == 0) ADDIN(0);
    if (ks == 2) ADDIN(1);
    __syncthreads();
    if (ks == 2) DUMP(0);
    __syncthreads();
    if (ks == 0) {
        ADDIN(0);
        float* outb = out + (size_t)b * 128 * 4096 + ho * 64;
        #pragma unroll
        for (int ft = 0; ft < 8; ++ft)
            #pragma unroll
            for (int r = 0; r < 4; ++r) {
                int f = ft * 16 + lu * 4 + r;
                outb[(size_t)f * 4096 + px] = acc[ft][r];
            }
    }
    #undef DUMP
    #undef ADDIN
}

extern "C" void kernel_launch(void* const* d_in, const int* in_sizes, int n_in,
                              void* d_out, int out_size, void* d_ws, size_t ws_size,
                              hipStream_t stream) {
    const float* x      = (const float*)d_in[0];
    const float* offset = (const float*)d_in[1];
    const float* mask   = (const float*)d_in[2];
    const float* weight = (const float*)d_in[3];
    float* out = (float*)d_out;

    ushort_t* xt  = (ushort_t*)d_ws;                       // 8 MiB (swizzled NHWC)
    ushort_t* wT2 = xt + (size_t)8 * 64 * 64 * 128;        // 288 KiB
    if (ws_size < (size_t)(8 * 64 * 64 * 128 + 9 * 16384) * 2) return;

    prep_all<<<4672, 256, 0, stream>>>(x, weight, xt, wT2);
    dcn_main<<<512, 1024, 0, stream>>>(offset, mask, xt, wT2, out);
}

// Round 21
// 40.778 us; speedup vs baseline: 1.0055x; 1.0055x over previous
//
#include <hip/hip_runtime.h>
#include <hip/hip_bf16.h>

typedef __attribute__((ext_vector_type(8))) short bf16x8;
typedef __attribute__((ext_vector_type(4))) float f32x4;
typedef __attribute__((ext_vector_type(2))) float f32x2;
typedef unsigned int uint32;
typedef unsigned short ushort_t;
typedef __attribute__((ext_vector_type(4))) uint32 u32x4;

#define SB0() __builtin_amdgcn_sched_barrier(0)

__device__ __forceinline__ ushort_t f2bf(float f) {
    unsigned int u = __float_as_uint(f);
    u = (u + 0x7FFFu + ((u >> 16) & 1u)) >> 16;
    return (ushort_t)u;
}

__device__ __forceinline__ uint32 cvt_pk_bf16(float lo, float hi) {
    uint32 r;
    asm("v_cvt_pk_bf16_f32 %0, %1, %2" : "=v"(r) : "v"(lo), "v"(hi));
    return r;
}

// Forced-issue 16B global load (cannot be sunk by the scheduler); value is
// consumed only after an explicit full-drain vmcnt(0) -> count-independent,
// spill-safe (any extra VMEM just gets drained too).
template<int IMM>
__device__ __forceinline__ u32x4 gload(const char* p) {
    u32x4 r;
    asm volatile("global_load_dwordx4 %0, %1, off offset:%2"
                 : "=v"(r) : "v"(p), "n"(IMM));
    return r;
}

__device__ __forceinline__ void gload_lds16(const void* g, void* l) {
    __builtin_amdgcn_global_load_lds(
        (const __attribute__((address_space(1))) uint32*)g,
        (__attribute__((address_space(3))) uint32*)l, 16, 0, 0);
}

// Fused prep (R12/R15-proven):
//  blocks 0..4095: transpose x NCHW fp32 -> NHWC bf16 with per-record 16B
//    sub-chunk XOR swizzle (chunk (c>>3) stored at (c>>3)^(x&7)).
//  blocks 4096..4671: repack weight fragment-major (R5 layout).
__global__ __launch_bounds__(256) void prep_all(const float* __restrict__ x,
                                                const float* __restrict__ w,
                                                ushort_t* __restrict__ xt,
                                                ushort_t* __restrict__ wT2) {
    int bi = blockIdx.x;
    int t = threadIdx.x;
    if (bi >= 4096) {
        int idx = (bi - 4096) * 256 + t;   // 0..147455
        int j  = idx & 7;
        int f  = (idx >> 3) & 127;
        int lu = (idx >> 10) & 3;
        int ks = (idx >> 12) & 3;
        int tap = idx >> 14;
        int c = ks * 32 + lu * 8 + j;
        wT2[idx] = f2bf(w[((size_t)f * 128 + c) * 9 + tap]);
        return;
    }
    __shared__ float tile[32][33];
    int b = bi & 7;
    int r2 = bi >> 3;
    int wb = r2 & 1, cb = (r2 >> 1) & 3, y = r2 >> 3;
    int lw = t & 31, lc = t >> 5;
    #pragma unroll
    for (int pass = 0; pass < 4; ++pass) {
        int c = cb * 32 + lc + pass * 8;
        tile[lc + pass * 8][lw] = x[(((size_t)b * 128 + c) * 64 + y) * 64 + wb * 32 + lw];
    }
    __syncthreads();
    int cc = t & 31, xl = t >> 5;
    #pragma unroll
    for (int pass = 0; pass < 4; ++pass) {
        int xll = xl + pass * 8;
        int xx = wb * 32 + xll;
        int c = cb * 32 + cc;
        int c2 = (((c >> 3) ^ (xx & 7)) << 3) | (c & 7);   // record-local swizzle
        xt[(((size_t)b * 64 + y) * 64 + xx) * 128 + c2] = f2bf(tile[cc][xll]);
    }
}

__device__ __forceinline__ bf16x8 interp4(u32x4 c0, u32x4 c1, u32x4 c2, u32x4 c3,
                                          f32x4 wv) {
    uint32 rr[4];
    #pragma unroll
    for (int i = 0; i < 4; ++i) {
        f32x2 a, s;
        uint32 u = c0[i];
        a.x = __uint_as_float(u << 16); a.y = __uint_as_float(u & 0xffff0000u);
        s = a * wv.x;
        u = c1[i];
        a.x = __uint_as_float(u << 16); a.y = __uint_as_float(u & 0xffff0000u);
        s += a * wv.y;
        u = c2[i];
        a.x = __uint_as_float(u << 16); a.y = __uint_as_float(u & 0xffff0000u);
        s += a * wv.z;
        u = c3[i];
        a.x = __uint_as_float(u << 16); a.y = __uint_as_float(u & 0xffff0000u);
        s += a * wv.w;
        rr[i] = cvt_pk_bf16(s.x, s.y);
    }
    u32x4 q = {rr[0], rr[1], rr[2], rr[3]};
    return __builtin_bit_cast(bf16x8, q);
}

// Block = 1024 thr = 16 waves = {4 pxg} x {4 ks}; one (b,ho) row (64 px x 128 F).
// Wave tile: 16px x 128F x 32ch, zero gather/interp duplication.
// 9-row LDS window (wave-level fallback ~2%, execz-skipped).
// Per tap: 8 A-fragment loads issued via asm volatile at tap top (un-sinkable),
// consumed after interp + vmcnt(0)+SB0 full drain. Session-best structure
// (R15/R19 family); epilogue compressed to a single-stage 3-slot reduce
// (5 barriers -> 2; 100 KB overlay <= 144 KB window).
__global__ __launch_bounds__(1024, 4) void dcn_main(
    const float* __restrict__ offset, const float* __restrict__ mask,
    const ushort_t* __restrict__ xt, const ushort_t* __restrict__ wT2,
    float* __restrict__ out)
{
    __shared__ ushort_t xwin[9 * 64 * 128];  // 144 KB; overlaid by `red` in epilogue
    __shared__ float  pws_l[9][64][4];       // 9 KB
    __shared__ uint32 pos_l[9][64];          // 2.25 KB

    int bi = blockIdx.x;
    int b = bi & 7, ho = bi >> 3;            // batch <-> XCD
    int t = threadIdx.x, lane = t & 63, wid = t >> 6;
    int pxg = wid & 3, ks = wid >> 2;
    int p = lane & 15, lu = lane >> 4;
    int px = pxg * 16 + p;
    int row0 = min(max(ho - 4, 0), 55);      // window rows [row0, row0+9)

    const char* xgb = (const char*)xt + (size_t)b * (64 * 64 * 256);

    // ---- prologue: stage 9-row window (async) + sampling params ----
    {
        const char* ws = xgb + ((size_t)row0 << 14);
        #pragma unroll
        for (int r = 0; r < 9; ++r)
            gload_lds16(ws + (r * 1024 + t) * 16, (char*)xwin + (r * 1024 + t) * 16);
    }
    if (t < 576) {
        int k = t >> 6, pi = t & 63;
        int ki = k / 3, kj = k - ki * 3;
        float dy = offset[(((size_t)b * 18 + 2 * k)     * 64 + ho) * 64 + pi];
        float dx = offset[(((size_t)b * 18 + 2 * k + 1) * 64 + ho) * 64 + pi];
        float m  = mask  [(((size_t)b * 9  + k)         * 64 + ho) * 64 + pi];
        float py = (float)(ho - 1 + ki) + dy;
        float px_ = (float)(pi - 1 + kj) + dx;
        float y0f = floorf(py), x0f = floorf(px_);
        float ly = py - y0f, lx = px_ - x0f;
        float hy = 1.f - ly, hx = 1.f - lx;
        int y0 = (int)y0f, x0 = (int)x0f;
        int y1 = y0 + 1, x1 = x0 + 1;
        float vy0 = (y0 >= 0 && y0 < 64) ? 1.f : 0.f;
        float vy1 = (y1 >= 0 && y1 < 64) ? 1.f : 0.f;
        float vx0 = (x0 >= 0 && x0 < 64) ? 1.f : 0.f;
        float vx1 = (x1 >= 0 && x1 < 64) ? 1.f : 0.f;
        pws_l[k][pi][0] = hy * hx * m * vy0 * vx0;
        pws_l[k][pi][1] = hy * lx * m * vy0 * vx1;
        pws_l[k][pi][2] = ly * hx * m * vy1 * vx0;
        pws_l[k][pi][3] = ly * lx * m * vy1 * vx1;
        int y0c = min(max(y0, 0), 63), y1c = min(max(y1, 0), 63);
        int x0c = min(max(x0, 0), 63), x1c = min(max(x1, 0), 63);
        pos_l[k][pi] = (uint32)(y0c * 64 + x0c) | ((uint32)(y1c * 64 + x1c) << 16);
    }
    __syncthreads();   // window + params ready (drains global_load_lds)

    f32x4 acc[8];
    #pragma unroll
    for (int i = 0; i < 8; ++i) acc[i] = (f32x4){0.f, 0.f, 0.f, 0.f};

    int klu = ks * 64 + lu * 16;   // this lane's 16B slice within a 256B record
    const char* abase = (const char*)wT2 + (lu * 128 + p) * 16;

    #pragma unroll 1
    for (int tap = 0; tap < 9; ++tap) {
        // ---- issue this tap's 8 A-frag loads (asm: cannot be sunk) ----
        const char* ab = abase + (size_t)(tap * 4 + ks) * 8192;
        u32x4 a0 = gload<0>(ab),    a1 = gload<256>(ab);
        u32x4 a2 = gload<512>(ab),  a3 = gload<768>(ab);
        u32x4 a4 = gload<1024>(ab), a5 = gload<1280>(ab);
        u32x4 a6 = gload<1536>(ab), a7 = gload<1792>(ab);
        SB0();   // pin issue point; ~150-250cy of gather+interp follows

        // ---- B frag: 4-corner gather from LDS window + rare fixup ----
        uint32 pp = pos_l[tap][px];
        int i00 = pp & 0xffffu, i11 = pp >> 16;
        int y0c = i00 >> 6, x0c = i00 & 63;
        int y1c = i11 >> 6, x1c = i11 & 63;
        u32x4 g[4];
        uint32 rec[4];
        #pragma unroll
        for (int c = 0; c < 4; ++c) {
            int yc = (c < 2) ? y0c : y1c;
            int xc = (c & 1) ? x1c : x0c;
            int rl = yc - row0;
            int off = klu ^ ((xc & 7) << 4);
            bool inw = (unsigned)rl < 9u;
            rec[c] = (uint32)(((yc * 64 + xc) << 8) + off) | (inw ? 0x80000000u : 0u);
            const char* lp = (const char*)xwin + (((inw ? rl : 0) * 64 + xc) << 8) + off;
            g[c] = *(const u32x4*)lp;
        }
        #pragma unroll
        for (int c = 0; c < 4; ++c) {
            if (!(rec[c] & 0x80000000u))   // ~2%/wave, execz-skipped; loads are
                g[c] = *(const u32x4*)(xgb + (rec[c] & 0x7fffffffu));  // younger than A
        }
        f32x4 wv = *(const f32x4*)pws_l[tap][px];
        bf16x8 bb = interp4(g[0], g[1], g[2], g[3], wv);

        // ---- full drain: A-frags (and anything else) complete; rule #18 fence ----
        asm volatile("s_waitcnt vmcnt(0)" ::: "memory");
        SB0();

        acc[0] = __builtin_amdgcn_mfma_f32_16x16x32_bf16(__builtin_bit_cast(bf16x8, a0), bb, acc[0], 0, 0, 0);
        acc[1] = __builtin_amdgcn_mfma_f32_16x16x32_bf16(__builtin_bit_cast(bf16x8, a1), bb, acc[1], 0, 0, 0);
        acc[2] = __builtin_amdgcn_mfma_f32_16x16x32_bf16(__builtin_bit_cast(bf16x8, a2), bb, acc[2], 0, 0, 0);
        acc[3] = __builtin_amdgcn_mfma_f32_16x16x32_bf16(__builtin_bit_cast(bf16x8, a3), bb, acc[3], 0, 0, 0);
        acc[4] = __builtin_amdgcn_mfma_f32_16x16x32_bf16(__builtin_bit_cast(bf16x8, a4), bb, acc[4], 0, 0, 0);
        acc[5] = __builtin_amdgcn_mfma_f32_16x16x32_bf16(__builtin_bit_cast(bf16x8, a5), bb, acc[5], 0, 0, 0);
        acc[6] = __builtin_amdgcn_mfma_f32_16x16x32_bf16(__builtin_bit_cast(bf16x8, a6), bb, acc[6], 0, 0, 0);
        acc[7] = __builtin_amdgcn_mfma_f32_16x16x32_bf16(__builtin_bit_cast(bf16x8, a7), bb, acc[7], 0, 0, 0);
    }

    // ---- epilogue: single-stage 4-way ks reduce (3 slots, stride 65) ----
    __syncthreads();             // all waves done reading xwin
    float* red = (float*)xwin;   // 3 slots x [128 f][stride 65] = 99.8 KB <= 144 KB
    if (ks != 0) {
        int slot = ks - 1;
        #pragma unroll
        for (int ft = 0; ft < 8; ++ft)
            #pragma unroll
            for (int r = 0; r < 4; ++r)
                red[slot * 8320 + (ft * 16 + lu * 4 + r) * 65 + px] = acc[ft][r];
    }
    __syncthreads();
    if (ks == 0) {
        float* outb = out + (size_t)b * 128 * 4096 + ho * 64;
        #pragma unroll
        for (int ft = 0; ft < 8; ++ft)
            #pragma unroll
            for (int r = 0; r < 4; ++r) {
                int f = ft * 16 + lu * 4 + r;
                float v = acc[ft][r]
                        + red[0 * 8320 + f * 65 + px]
                        + red[1 * 8320 + f * 65 + px]
                        + red[2 * 8320 + f * 65 + px];
                outb[(size_t)f * 4096 + px] = v;
            }
    }
}

extern "C" void kernel_launch(void* const* d_in, const int* in_sizes, int n_in,
                              void* d_out, int out_size, void* d_ws, size_t ws_size,
                              hipStream_t stream) {
    const float* x      = (const float*)d_in[0];
    const float* offset = (const float*)d_in[1];
    const float* mask   = (const float*)d_in[2];
    const float* weight = (const float*)d_in[3];
    float* out = (float*)d_out;

    ushort_t* xt  = (ushort_t*)d_ws;                       // 8 MiB (swizzled NHWC)
    ushort_t* wT2 = xt + (size_t)8 * 64 * 64 * 128;        // 288 KiB
    if (ws_size < (size_t)(8 * 64 * 64 * 128 + 9 * 16384) * 2) return;

    prep_all<<<4672, 256, 0, stream>>>(x, weight, xt, wT2);
    dcn_main<<<512, 1024, 0, stream>>>(offset, mask, xt, wT2, out);
}